// Round 19
// baseline (233.090 us; speedup 1.0000x reference)
//
#include <hip/hip_runtime.h>
#include <hip/hip_bf16.h>
#include <math.h>

#define NF     16      // num features (K of low-rank projection)
#define INF    1024    // in_f
#define NPROTO 4096
#define NROWS  16384

typedef __attribute__((ext_vector_type(8))) short short8;   // 8 bf16 (4 VGPRs)
typedef __attribute__((ext_vector_type(4))) float f32x4;
typedef __attribute__((ext_vector_type(2))) float f32x2;

// round f32 -> bf16 (RNE) and return as f32 value
__device__ __forceinline__ float bf16_rne(float x) {
    unsigned u = __float_as_uint(x);
    unsigned r = (u + 0x7FFFu + ((u >> 16) & 1u)) & 0xFFFF0000u;
    return __uint_as_float(r);
}

// split f32 v into bf16 hi + bf16 lo (v ~= hi + lo, err ~2^-17 rel)
__device__ __forceinline__ void split_bf16(float v, unsigned short& hi, unsigned short& lo) {
    unsigned u  = __float_as_uint(v);
    unsigned r  = u + 0x7FFFu + ((u >> 16) & 1u);
    hi = (unsigned short)(r >> 16);
    float hf = __uint_as_float(r & 0xFFFF0000u);
    float rem = v - hf;
    unsigned u2 = __float_as_uint(rem);
    unsigned r2 = u2 + 0x7FFFu + ((u2 >> 16) & 1u);
    lo = (unsigned short)(r2 >> 16);
}

__device__ __forceinline__ float sigmoid5(float z) {
    return 1.0f / (1.0f + __expf(-5.0f * z));
}

// ---------------- R19 prep: coalescing-friendly lane = (row, k) ----------------
// Block 256 thr = 4 waves. Wave w, lane = r*16+k (r=lane>>4, k=lane&15):
// handles row blk*16 + w*4 + r, feature k. x/proto loads: 16 lanes share one
// address (hw broadcast, ~4 lines per instr instead of 64 txns). feat: 16
// rows, L1-hot (64 KB). Low VGPR, no butterfly, no LDS, no barrier.
// pe branch reproduces the OLD quantization arithmetic exactly (bit-identical
// q): same bf16 RNE, same group-sum association ((s0+s1)+(s2+s3), inner
// asum += ((|w0|+|w1|)+|w2|)+|w3| sequentially).
__global__ __launch_bounds__(256) void prep(
    const float* __restrict__ x, const float* __restrict__ feat,
    const float* __restrict__ proto,
    const float* __restrict__ theta, const float* __restrict__ alpha,
    const float* __restrict__ beta,
    unsigned short* __restrict__ Ph, unsigned short* __restrict__ Pl,
    unsigned short* __restrict__ Xh, unsigned short* __restrict__ Xl)
{
    const int lane = threadIdx.x & 63;
    const int w    = threadIdx.x >> 6;
    const int r    = lane >> 4;
    const int k    = lane & 15;
    const int blk  = blockIdx.x;
    const float* frow = feat + (size_t)k * INF;

    if (blk < NPROTO / 16) {
        // ---- pe: row R of prototypes ----
        const int R = blk * 16 + w * 4 + r;
        const float* prow = proto + (size_t)R * INF;
        const float th = fabsf(theta[0]);
        const float al = fabsf(alpha[0]);
        const float be = fabsf(beta[0]);

        float a0 = 0.f, a1 = 0.f, a2 = 0.f, a3 = 0.f;
#pragma unroll 1
        for (int g = 0; g < 16; ++g) {
            const float* pg = prow + g * 64;
            // pass A: group abs-sum, exact old association order
            float s[4];
#pragma unroll
            for (int sub = 0; sub < 4; ++sub) {
                float asum = 0.f;
#pragma unroll
                for (int j = 0; j < 16; j += 4) {
                    float4 w4 = *(const float4*)(pg + sub * 16 + j);
                    float p = ((fabsf(bf16_rne(w4.x)) + fabsf(bf16_rne(w4.y)))
                               + fabsf(bf16_rne(w4.z))) + fabsf(bf16_rne(w4.w));
                    asum += p;
                }
                s[sub] = asum;
            }
            float grp   = (s[0] + s[1]) + (s[2] + s[3]);
            float scale = fmaxf(bf16_rne(grp * (1.0f / 64.0f)), 1e-8f);
            float inv   = 1.0f / scale;
            // pass B: quantize (bit-identical to old) + dot with feat[k]
            const float* fg = frow + g * 64;
#pragma unroll
            for (int i = 0; i < 64; i += 4) {
                float4 w4 = *(const float4*)(pg + i);
                float4 f4 = *(const float4*)(fg + i);
                float q0 = fminf(fmaxf(rintf(bf16_rne(bf16_rne(w4.x) * inv)), -1.f), 1.f) * scale;
                float q1 = fminf(fmaxf(rintf(bf16_rne(bf16_rne(w4.y) * inv)), -1.f), 1.f) * scale;
                float q2 = fminf(fmaxf(rintf(bf16_rne(bf16_rne(w4.z) * inv)), -1.f), 1.f) * scale;
                float q3 = fminf(fmaxf(rintf(bf16_rne(bf16_rne(w4.w) * inv)), -1.f), 1.f) * scale;
                a0 = fmaf(q0, f4.x, a0);
                a1 = fmaf(q1, f4.y, a1);
                a2 = fmaf(q2, f4.z, a2);
                a3 = fmaf(q3, f4.w, a3);
            }
        }
        float pf = (a0 + a1) + (a2 + a3);
        float ps = sigmoid5(pf);
        float pa = pf * ps;
        unsigned short h0, l0, h1, l1;
        split_bf16(th * pa - al * (1.0f - ps), h0, l0);
        split_bf16(-be * pa, h1, l1);
        Ph[R * 32 + k]      = h0;  Pl[R * 32 + k]      = l0;
        Ph[R * 32 + 16 + k] = h1;  Pl[R * 32 + 16 + k] = l1;
    } else {
        // ---- xe: row R of x ----
        const int R = (blk - NPROTO / 16) * 16 + w * 4 + r;
        const float* xrow = x + (size_t)R * INF;
        float a0 = 0.f, a1 = 0.f, a2 = 0.f, a3 = 0.f;
#pragma unroll 8
        for (int i = 0; i < INF; i += 4) {
            float4 xv = *(const float4*)(xrow + i);
            float4 f4 = *(const float4*)(frow + i);
            a0 = fmaf(xv.x, f4.x, a0);
            a1 = fmaf(xv.y, f4.y, a1);
            a2 = fmaf(xv.z, f4.z, a2);
            a3 = fmaf(xv.w, f4.w, a3);
        }
        float xf = (a0 + a1) + (a2 + a3);
        float xs = sigmoid5(xf);
        unsigned short h0, l0, h1, l1;
        split_bf16(xf * xs, h0, l0);
        split_bf16(1.0f - xs, h1, l1);
        Xh[R * 32 + k]      = h0;  Xl[R * 32 + k]      = l0;
        Xh[R * 32 + 16 + k] = h1;  Xl[R * 32 + 16 + k] = l1;
    }
}

// ------- main: out = Xe (16384x32) @ Pe^T (4096x32), MFMA hi/lo -------
// R14 body verbatim — measured 45.3 us standalone (R18 algebra), ~5.9 TB/s
// effective write. 16x128 tile, 8 KiB LDS (20 blocks/CU), XOR-swizzled
// wave-private LDS transpose, NT f32x2 stores (512 B contiguous per instr).
__global__ __launch_bounds__(64) void main_mm_mfma(
    const unsigned short* __restrict__ Xh, const unsigned short* __restrict__ Xl,
    const unsigned short* __restrict__ Ph, const unsigned short* __restrict__ Pl,
    float* __restrict__ out)
{
    __shared__ float lds[16][128];      // 8 KiB, wave-private (1 wave/block)
    const int lane  = threadIdx.x & 63;
    const int m     = lane & 15;        // n within tile (C col)
    const int b     = lane >> 4;        // K-group / C row-group
    const int nbase = blockIdx.y * 16;
    const int ob    = blockIdx.x * 128;

    // B fragment (Xe): col = n, loaded once per wave
    const size_t boff = (size_t)(nbase + m) * 32 + b * 8;
    const short8 Bh = *(const short8*)(Xh + boff);
    const short8 Bl = *(const short8*)(Xl + boff);

    // col-XOR swizzle: logical dword c of row r stored at c ^ (4*(r&7))
    const int wsw = 4 * (m & 7);
    float* myrow = &lds[m][0];
#pragma unroll
    for (int t = 0; t < 8; ++t) {
        const size_t aoff = (size_t)(ob + t * 16 + m) * 32 + b * 8;
        const short8 Ah = *(const short8*)(Ph + aoff);
        const short8 Al = *(const short8*)(Pl + aoff);
        f32x4 acc = {0.f, 0.f, 0.f, 0.f};
        acc = __builtin_amdgcn_mfma_f32_16x16x32_bf16(Ah, Bh, acc, 0, 0, 0);
        acc = __builtin_amdgcn_mfma_f32_16x16x32_bf16(Ah, Bl, acc, 0, 0, 0);
        acc = __builtin_amdgcn_mfma_f32_16x16x32_bf16(Al, Bh, acc, 0, 0, 0);
        acc = __builtin_amdgcn_mfma_f32_16x16x32_bf16(Al, Bl, acc, 0, 0, 0);
        *(f32x4*)(myrow + ((t * 16 + b * 4) ^ wsw)) = acc;  // 4-aligned XOR, <128
    }

    const float* src = &lds[0][0];
#pragma unroll
    for (int r = 0; r < 16; ++r) {
        f32x2 v = *(const f32x2*)(src + r * 128 + ((lane * 2) ^ (4 * (r & 7))));
        f32x2* dst = (f32x2*)(out + (size_t)(nbase + r) * NPROTO + ob + lane * 2);
        __builtin_nontemporal_store(v, dst);
    }
}

extern "C" void kernel_launch(void* const* d_in, const int* in_sizes, int n_in,
                              void* d_out, int out_size, void* d_ws, size_t ws_size,
                              hipStream_t stream) {
    const float* x     = (const float*)d_in[0];
    const float* feat  = (const float*)d_in[1];
    const float* proto = (const float*)d_in[2];
    const float* theta = (const float*)d_in[3];
    const float* alpha = (const float*)d_in[4];
    const float* beta  = (const float*)d_in[5];
    float* out = (float*)d_out;

    unsigned short* Ph = (unsigned short*)d_ws;          // 256 KiB
    unsigned short* Pl = Ph + (size_t)NPROTO * 32;       // 256 KiB
    unsigned short* Xh = Pl + (size_t)NPROTO * 32;       // 1 MiB
    unsigned short* Xl = Xh + (size_t)NROWS * 32;        // 1 MiB

    prep<<<dim3(NPROTO / 16 + NROWS / 16), 256, 0, stream>>>(
        x, feat, proto, theta, alpha, beta, Ph, Pl, Xh, Xl);
    main_mm_mfma<<<dim3(NPROTO / 128, NROWS / 16), 64, 0, stream>>>(Xh, Xl, Ph, Pl, out);
}

// Round 20
// 107.212 us; speedup vs baseline: 2.1741x; 2.1741x over previous
//
#include <hip/hip_runtime.h>
#include <hip/hip_bf16.h>
#include <math.h>

#define NF     16
#define INF    1024
#define NPROTO 4096
#define NROWS  16384

typedef __attribute__((ext_vector_type(8))) short short8;   // 8 bf16 (4 VGPRs)
typedef __attribute__((ext_vector_type(4))) unsigned short ushort4v;
typedef __attribute__((ext_vector_type(4))) float f32x4;
typedef __attribute__((ext_vector_type(2))) float f32x2;

__device__ __forceinline__ float bf16_rne(float x) {
    unsigned u = __float_as_uint(x);
    unsigned r = (u + 0x7FFFu + ((u >> 16) & 1u)) & 0xFFFF0000u;
    return __uint_as_float(r);
}
__device__ __forceinline__ unsigned short bf16_hi(float v) {
    unsigned u = __float_as_uint(v);
    return (unsigned short)((u + 0x7FFFu + ((u >> 16) & 1u)) >> 16);
}
// split f32 v into bf16 hi + bf16 lo (v ~= hi + lo)
__device__ __forceinline__ void split_bf16(float v, unsigned short& hi, unsigned short& lo) {
    unsigned u  = __float_as_uint(v);
    unsigned r  = u + 0x7FFFu + ((u >> 16) & 1u);
    hi = (unsigned short)(r >> 16);
    float hf = __uint_as_float(r & 0xFFFF0000u);
    lo = bf16_hi(v - hf);
}
__device__ __forceinline__ float sigmoid5(float z) {
    return 1.0f / (1.0f + __expf(-5.0f * z));
}

// ---- B-fragment precompute: feat -> bf16 hi/lo MFMA fragments ----
// BF[kstep][lane] (short8): lane(n=lane&15, b=lane>>4) = feat[n][kstep*32+b*8..+7]
__global__ __launch_bounds__(256) void bfrag_kernel(
    const float* __restrict__ feat,
    unsigned short* __restrict__ BFh, unsigned short* __restrict__ BFl)
{
    const int t = blockIdx.x * 256 + threadIdx.x;    // 0..2047
    const int kstep = t >> 6, lane = t & 63;
    const int n = lane & 15, b = lane >> 4;
    const float* src = feat + (size_t)n * INF + kstep * 32 + b * 8;
    float4 v0 = *(const float4*)(src);
    float4 v1 = *(const float4*)(src + 4);
    unsigned short h[8], l[8];
    split_bf16(v0.x, h[0], l[0]); split_bf16(v0.y, h[1], l[1]);
    split_bf16(v0.z, h[2], l[2]); split_bf16(v0.w, h[3], l[3]);
    split_bf16(v1.x, h[4], l[4]); split_bf16(v1.y, h[5], l[5]);
    split_bf16(v1.z, h[6], l[6]); split_bf16(v1.w, h[7], l[7]);
#pragma unroll
    for (int e = 0; e < 8; ++e) { BFh[t * 8 + e] = h[e]; BFl[t * 8 + e] = l[e]; }
}

// ---- prep: MFMA projection. blocks [0,256) = pe, [256,1280) = xe ----
// 1 wave/block. Stage 16 rows coalesced (1 KB/instr) -> convert -> LDS in
// fragment-major layout -> 32 MFMA k-steps vs BF -> epilogue -> Xe/Pe.
// frag byte(kstep,b,m,e) = (kstep*1024 + b*256 + m*16 + e*2) ^ ((kstep&7)<<4)
// pe: q = clamp(rint(rne(rne(w)*inv)))*scale is EXACT bf16 (single plane).
__global__ __launch_bounds__(64) void prep(
    const float* __restrict__ x, const float* __restrict__ proto,
    const float* __restrict__ theta, const float* __restrict__ alpha,
    const float* __restrict__ beta,
    const unsigned short* __restrict__ BFh, const unsigned short* __restrict__ BFl,
    unsigned short* __restrict__ Ph, unsigned short* __restrict__ Pl,
    unsigned short* __restrict__ Xh, unsigned short* __restrict__ Xl)
{
    __shared__ unsigned short ldsA[32768];   // 64 KB: hi plane [0,16384), lo [16384,32768)
    const int lane = threadIdx.x & 63;
    const int blk  = blockIdx.x;
    const bool is_pe = (blk < NPROTO / 16);
    const int rowbase = (is_pe ? blk : blk - NPROTO / 16) * 16;
    const float* srcm = is_pe ? proto : x;

    // ---------- staging ----------
    if (is_pe) {
#pragma unroll 4
        for (int j = 0; j < 64; ++j) {
            const int flat = j * 256 + lane * 4;
            float4 w4 = *(const float4*)(srcm + (size_t)rowbase * INF + flat);
            float wb0 = bf16_rne(w4.x), wb1 = bf16_rne(w4.y);
            float wb2 = bf16_rne(w4.z), wb3 = bf16_rne(w4.w);
            float p = ((fabsf(wb0) + fabsf(wb1)) + fabsf(wb2)) + fabsf(wb3);
            p += __shfl_xor(p, 1, 64);
            p += __shfl_xor(p, 2, 64);
            p += __shfl_xor(p, 4, 64);
            p += __shfl_xor(p, 8, 64);     // 16-lane group = one 64-elem quant group
            float scale = fmaxf(bf16_rne(p * (1.0f / 64.0f)), 1e-8f);
            float inv = 1.0f / scale;
            float q0 = fminf(fmaxf(rintf(bf16_rne(wb0 * inv)), -1.f), 1.f) * scale;
            float q1 = fminf(fmaxf(rintf(bf16_rne(wb1 * inv)), -1.f), 1.f) * scale;
            float q2 = fminf(fmaxf(rintf(bf16_rne(wb2 * inv)), -1.f), 1.f) * scale;
            float q3 = fminf(fmaxf(rintf(bf16_rne(wb3 * inv)), -1.f), 1.f) * scale;
            const int c = flat & 1023, r = flat >> 10;
            const int kst = c >> 5, b2 = (c >> 3) & 3, e = c & 7;
            const int byte = (kst * 1024 + b2 * 256 + r * 16 + e * 2) ^ ((kst & 7) << 4);
            ushort4v hq = { (unsigned short)(__float_as_uint(q0) >> 16),
                            (unsigned short)(__float_as_uint(q1) >> 16),
                            (unsigned short)(__float_as_uint(q2) >> 16),
                            (unsigned short)(__float_as_uint(q3) >> 16) };
            *(ushort4v*)((char*)ldsA + byte) = hq;   // exact bf16, single plane
        }
    } else {
#pragma unroll 4
        for (int j = 0; j < 64; ++j) {
            const int flat = j * 256 + lane * 4;
            float4 w4 = *(const float4*)(srcm + (size_t)rowbase * INF + flat);
            unsigned short h0,l0,h1,l1,h2,l2,h3,l3;
            split_bf16(w4.x, h0, l0); split_bf16(w4.y, h1, l1);
            split_bf16(w4.z, h2, l2); split_bf16(w4.w, h3, l3);
            const int c = flat & 1023, r = flat >> 10;
            const int kst = c >> 5, b2 = (c >> 3) & 3, e = c & 7;
            const int byte = (kst * 1024 + b2 * 256 + r * 16 + e * 2) ^ ((kst & 7) << 4);
            ushort4v hv = {h0,h1,h2,h3}, lv = {l0,l1,l2,l3};
            *(ushort4v*)((char*)ldsA + byte)         = hv;
            *(ushort4v*)((char*)ldsA + 32768 + byte) = lv;
        }
    }
    // single wave: compiler lgkmcnt covers ds_write -> ds_read RAW

    // ---------- MFMA: acc[4] = rows x features ----------
    const int m = lane & 15, b = lane >> 4;
    f32x4 acc = {0.f, 0.f, 0.f, 0.f};
#pragma unroll 2
    for (int kstep = 0; kstep < 32; ++kstep) {
        const int abyte = (kstep * 1024 + b * 256 + m * 16) ^ ((kstep & 7) << 4);
        short8 Ah = *(const short8*)((char*)ldsA + abyte);
        short8 Bh = *(const short8*)(BFh + ((size_t)kstep * 64 + lane) * 8);
        short8 Bl = *(const short8*)(BFl + ((size_t)kstep * 64 + lane) * 8);
        acc = __builtin_amdgcn_mfma_f32_16x16x32_bf16(Ah, Bh, acc, 0, 0, 0);
        acc = __builtin_amdgcn_mfma_f32_16x16x32_bf16(Ah, Bl, acc, 0, 0, 0);
        if (!is_pe) {
            short8 Al = *(const short8*)((char*)ldsA + 32768 + abyte);
            acc = __builtin_amdgcn_mfma_f32_16x16x32_bf16(Al, Bh, acc, 0, 0, 0);
            acc = __builtin_amdgcn_mfma_f32_16x16x32_bf16(Al, Bl, acc, 0, 0, 0);
        }
    }

    // ---------- epilogue: C row = b*4+reg (local row), col = m (feature) ----------
    if (is_pe) {
        const float th = fabsf(theta[0]);
        const float al = fabsf(alpha[0]);
        const float be = fabsf(beta[0]);
#pragma unroll
        for (int reg = 0; reg < 4; ++reg) {
            const int row = rowbase + b * 4 + reg;
            float pf = acc[reg];
            float ps = sigmoid5(pf);
            float pa = pf * ps;
            unsigned short h0,l0,h1,l1;
            split_bf16(th * pa - al * (1.0f - ps), h0, l0);
            split_bf16(-be * pa, h1, l1);
            Ph[row * 32 + m]      = h0;  Pl[row * 32 + m]      = l0;
            Ph[row * 32 + 16 + m] = h1;  Pl[row * 32 + 16 + m] = l1;
        }
    } else {
#pragma unroll
        for (int reg = 0; reg < 4; ++reg) {
            const int row = rowbase + b * 4 + reg;
            float xf = acc[reg];
            float xs = sigmoid5(xf);
            unsigned short h0,l0,h1,l1;
            split_bf16(xf * xs, h0, l0);
            split_bf16(1.0f - xs, h1, l1);
            Xh[row * 32 + m]      = h0;  Xl[row * 32 + m]      = l0;
            Xh[row * 32 + 16 + m] = h1;  Xl[row * 32 + 16 + m] = l1;
        }
    }
}

// ------- main: R14 body verbatim — 45.3 us standalone (R18 algebra) -------
__global__ __launch_bounds__(64) void main_mm_mfma(
    const unsigned short* __restrict__ Xh, const unsigned short* __restrict__ Xl,
    const unsigned short* __restrict__ Ph, const unsigned short* __restrict__ Pl,
    float* __restrict__ out)
{
    __shared__ float lds[16][128];      // 8 KiB, wave-private (1 wave/block)
    const int lane  = threadIdx.x & 63;
    const int m     = lane & 15;
    const int b     = lane >> 4;
    const int nbase = blockIdx.y * 16;
    const int ob    = blockIdx.x * 128;

    const size_t boff = (size_t)(nbase + m) * 32 + b * 8;
    const short8 Bh = *(const short8*)(Xh + boff);
    const short8 Bl = *(const short8*)(Xl + boff);

    const int wsw = 4 * (m & 7);
    float* myrow = &lds[m][0];
#pragma unroll
    for (int t = 0; t < 8; ++t) {
        const size_t aoff = (size_t)(ob + t * 16 + m) * 32 + b * 8;
        const short8 Ah = *(const short8*)(Ph + aoff);
        const short8 Al = *(const short8*)(Pl + aoff);
        f32x4 acc = {0.f, 0.f, 0.f, 0.f};
        acc = __builtin_amdgcn_mfma_f32_16x16x32_bf16(Ah, Bh, acc, 0, 0, 0);
        acc = __builtin_amdgcn_mfma_f32_16x16x32_bf16(Ah, Bl, acc, 0, 0, 0);
        acc = __builtin_amdgcn_mfma_f32_16x16x32_bf16(Al, Bh, acc, 0, 0, 0);
        acc = __builtin_amdgcn_mfma_f32_16x16x32_bf16(Al, Bl, acc, 0, 0, 0);
        *(f32x4*)(myrow + ((t * 16 + b * 4) ^ wsw)) = acc;
    }

    const float* src = &lds[0][0];
#pragma unroll
    for (int r = 0; r < 16; ++r) {
        f32x2 v = *(const f32x2*)(src + r * 128 + ((lane * 2) ^ (4 * (r & 7))));
        f32x2* dst = (f32x2*)(out + (size_t)(nbase + r) * NPROTO + ob + lane * 2);
        __builtin_nontemporal_store(v, dst);
    }
}

extern "C" void kernel_launch(void* const* d_in, const int* in_sizes, int n_in,
                              void* d_out, int out_size, void* d_ws, size_t ws_size,
                              hipStream_t stream) {
    const float* x     = (const float*)d_in[0];
    const float* feat  = (const float*)d_in[1];
    const float* proto = (const float*)d_in[2];
    const float* theta = (const float*)d_in[3];
    const float* alpha = (const float*)d_in[4];
    const float* beta  = (const float*)d_in[5];
    float* out = (float*)d_out;

    unsigned short* Ph  = (unsigned short*)d_ws;          // 256 KiB
    unsigned short* Pl  = Ph + (size_t)NPROTO * 32;       // 256 KiB
    unsigned short* Xh  = Pl + (size_t)NPROTO * 32;       // 1 MiB
    unsigned short* Xl  = Xh + (size_t)NROWS * 32;        // 1 MiB
    unsigned short* BFh = Xl + (size_t)NROWS * 32;        // 32 KiB
    unsigned short* BFl = BFh + (size_t)2048 * 8;         // 32 KiB

    bfrag_kernel<<<dim3(8), 256, 0, stream>>>(feat, BFh, BFl);
    prep<<<dim3(NPROTO / 16 + NROWS / 16), 64, 0, stream>>>(
        x, proto, theta, alpha, beta, BFh, BFl, Ph, Pl, Xh, Xl);
    main_mm_mfma<<<dim3(NPROTO / 128, NROWS / 16), 64, 0, stream>>>(Xh, Xl, Ph, Pl, out);
}

// Round 21
// 75.381 us; speedup vs baseline: 3.0922x; 1.4223x over previous
//
#include <hip/hip_runtime.h>
#include <hip/hip_bf16.h>
#include <math.h>

#define NF     16
#define INF    1024
#define NPROTO 4096
#define NROWS  16384

typedef __attribute__((ext_vector_type(8))) short short8;   // 8 bf16 (4 VGPRs)
typedef __attribute__((ext_vector_type(4))) float f32x4;
typedef __attribute__((ext_vector_type(2))) float f32x2;

__device__ __forceinline__ float bf16_rne(float x) {
    unsigned u = __float_as_uint(x);
    unsigned r = (u + 0x7FFFu + ((u >> 16) & 1u)) & 0xFFFF0000u;
    return __uint_as_float(r);
}
__device__ __forceinline__ unsigned short bf16_hi(float v) {
    unsigned u = __float_as_uint(v);
    return (unsigned short)((u + 0x7FFFu + ((u >> 16) & 1u)) >> 16);
}
// split f32 v into bf16 hi + bf16 lo (v ~= hi + lo)
__device__ __forceinline__ void split_bf16(float v, unsigned short& hi, unsigned short& lo) {
    unsigned u  = __float_as_uint(v);
    unsigned r  = u + 0x7FFFu + ((u >> 16) & 1u);
    hi = (unsigned short)(r >> 16);
    float hf = __uint_as_float(r & 0xFFFF0000u);
    lo = bf16_hi(v - hf);
}
__device__ __forceinline__ float sigmoid5(float z) {
    return 1.0f / (1.0f + __expf(-5.0f * z));
}

// ---- B-fragment precompute: feat -> bf16 hi/lo MFMA fragments ----
// BF[kstep][lane] (short8): lane(n=lane&15, b=lane>>4) = feat[n][kstep*32+b*8..+7]
__global__ __launch_bounds__(256) void bfrag_kernel(
    const float* __restrict__ feat,
    unsigned short* __restrict__ BFh, unsigned short* __restrict__ BFl)
{
    const int t = blockIdx.x * 256 + threadIdx.x;    // 0..2047
    const int kstep = t >> 6, lane = t & 63;
    const int n = lane & 15, b = lane >> 4;
    const float* src = feat + (size_t)n * INF + kstep * 32 + b * 8;
    float4 v0 = *(const float4*)(src);
    float4 v1 = *(const float4*)(src + 4);
    unsigned short h[8], l[8];
    split_bf16(v0.x, h[0], l[0]); split_bf16(v0.y, h[1], l[1]);
    split_bf16(v0.z, h[2], l[2]); split_bf16(v0.w, h[3], l[3]);
    split_bf16(v1.x, h[4], l[4]); split_bf16(v1.y, h[5], l[5]);
    split_bf16(v1.z, h[6], l[6]); split_bf16(v1.w, h[7], l[7]);
#pragma unroll
    for (int e = 0; e < 8; ++e) { BFh[t * 8 + e] = h[e]; BFl[t * 8 + e] = l[e]; }
}

// ---- R21 prep: LDS-FREE direct-fragment MFMA projection ----
// 1 wave/block, no LDS, no barrier. Lane(m=lane&15, b=lane>>4) loads its A
// fragment straight from global (row rowbase+m, elems kstep*32+b*8..+7),
// converts in-register, MFMAs against BF (L2-hot). VGPR-capped at 128 ->
// 4 waves/SIMD (vs R20's LDS-capped 0.5).
// pe: per 64-elem group, abs-sum via in-lane sequential packets + shfl_xor
// b-tree ((p0+p1)+(p2+p3) association, matching original shape); q exact bf16.
__global__ __launch_bounds__(64, 4) void prep(
    const float* __restrict__ x, const float* __restrict__ proto,
    const float* __restrict__ theta, const float* __restrict__ alpha,
    const float* __restrict__ beta,
    const unsigned short* __restrict__ BFh, const unsigned short* __restrict__ BFl,
    unsigned short* __restrict__ Ph, unsigned short* __restrict__ Pl,
    unsigned short* __restrict__ Xh, unsigned short* __restrict__ Xl)
{
    const int lane = threadIdx.x & 63;
    const int m = lane & 15, b = lane >> 4;
    const int blk = blockIdx.x;
    const bool is_pe = (blk < NPROTO / 16);
    const int rowbase = (is_pe ? blk : blk - NPROTO / 16) * 16;
    const float* rowp = (is_pe ? proto : x) + (size_t)(rowbase + m) * INF;

    f32x4 acc = {0.f, 0.f, 0.f, 0.f};

    if (is_pe) {
#pragma unroll 2
        for (int g = 0; g < 16; ++g) {
            // group g = row elems [g*64, g*64+64); this lane holds 16 of them:
            // kstep 2g:   [g*64 + b*8, +8)    (v0,v1)
            // kstep 2g+1: [g*64+32 + b*8, +8) (v2,v3)
            const float* pg = rowp + g * 64 + b * 8;
            float4 v0 = *(const float4*)(pg);
            float4 v1 = *(const float4*)(pg + 4);
            float4 v2 = *(const float4*)(pg + 32);
            float4 v3 = *(const float4*)(pg + 36);
            float w0 = bf16_rne(v0.x), w1 = bf16_rne(v0.y), w2 = bf16_rne(v0.z), w3 = bf16_rne(v0.w);
            float w4 = bf16_rne(v1.x), w5 = bf16_rne(v1.y), w6 = bf16_rne(v1.z), w7 = bf16_rne(v1.w);
            float w8 = bf16_rne(v2.x), w9 = bf16_rne(v2.y), wa = bf16_rne(v2.z), wb = bf16_rne(v2.w);
            float wc = bf16_rne(v3.x), wd = bf16_rne(v3.y), we = bf16_rne(v3.z), wf = bf16_rne(v3.w);
            // in-lane packets, sequential accumulation (original shape)
            float p0 = ((fabsf(w0) + fabsf(w1)) + fabsf(w2)) + fabsf(w3);
            float p1 = ((fabsf(w4) + fabsf(w5)) + fabsf(w6)) + fabsf(w7);
            float p2 = ((fabsf(w8) + fabsf(w9)) + fabsf(wa)) + fabsf(wb);
            float p3 = ((fabsf(wc) + fabsf(wd)) + fabsf(we)) + fabsf(wf);
            float p = ((p0 + p1) + p2) + p3;
            p += __shfl_xor(p, 16, 64);   // b-lane tree: (q0+q1)+(q2+q3)
            p += __shfl_xor(p, 32, 64);
            float scale = fmaxf(bf16_rne(p * (1.0f / 64.0f)), 1e-8f);
            float inv = 1.0f / scale;
            short8 A0, A1;
            A0[0] = (short)bf16_hi(fminf(fmaxf(rintf(bf16_rne(w0 * inv)), -1.f), 1.f) * scale);
            A0[1] = (short)bf16_hi(fminf(fmaxf(rintf(bf16_rne(w1 * inv)), -1.f), 1.f) * scale);
            A0[2] = (short)bf16_hi(fminf(fmaxf(rintf(bf16_rne(w2 * inv)), -1.f), 1.f) * scale);
            A0[3] = (short)bf16_hi(fminf(fmaxf(rintf(bf16_rne(w3 * inv)), -1.f), 1.f) * scale);
            A0[4] = (short)bf16_hi(fminf(fmaxf(rintf(bf16_rne(w4 * inv)), -1.f), 1.f) * scale);
            A0[5] = (short)bf16_hi(fminf(fmaxf(rintf(bf16_rne(w5 * inv)), -1.f), 1.f) * scale);
            A0[6] = (short)bf16_hi(fminf(fmaxf(rintf(bf16_rne(w6 * inv)), -1.f), 1.f) * scale);
            A0[7] = (short)bf16_hi(fminf(fmaxf(rintf(bf16_rne(w7 * inv)), -1.f), 1.f) * scale);
            A1[0] = (short)bf16_hi(fminf(fmaxf(rintf(bf16_rne(w8 * inv)), -1.f), 1.f) * scale);
            A1[1] = (short)bf16_hi(fminf(fmaxf(rintf(bf16_rne(w9 * inv)), -1.f), 1.f) * scale);
            A1[2] = (short)bf16_hi(fminf(fmaxf(rintf(bf16_rne(wa * inv)), -1.f), 1.f) * scale);
            A1[3] = (short)bf16_hi(fminf(fmaxf(rintf(bf16_rne(wb * inv)), -1.f), 1.f) * scale);
            A1[4] = (short)bf16_hi(fminf(fmaxf(rintf(bf16_rne(wc * inv)), -1.f), 1.f) * scale);
            A1[5] = (short)bf16_hi(fminf(fmaxf(rintf(bf16_rne(wd * inv)), -1.f), 1.f) * scale);
            A1[6] = (short)bf16_hi(fminf(fmaxf(rintf(bf16_rne(we * inv)), -1.f), 1.f) * scale);
            A1[7] = (short)bf16_hi(fminf(fmaxf(rintf(bf16_rne(wf * inv)), -1.f), 1.f) * scale);
            const short8 Bh0 = *(const short8*)(BFh + ((size_t)(2 * g) * 64 + lane) * 8);
            const short8 Bl0 = *(const short8*)(BFl + ((size_t)(2 * g) * 64 + lane) * 8);
            const short8 Bh1 = *(const short8*)(BFh + ((size_t)(2 * g + 1) * 64 + lane) * 8);
            const short8 Bl1 = *(const short8*)(BFl + ((size_t)(2 * g + 1) * 64 + lane) * 8);
            acc = __builtin_amdgcn_mfma_f32_16x16x32_bf16(A0, Bh0, acc, 0, 0, 0);
            acc = __builtin_amdgcn_mfma_f32_16x16x32_bf16(A0, Bl0, acc, 0, 0, 0);
            acc = __builtin_amdgcn_mfma_f32_16x16x32_bf16(A1, Bh1, acc, 0, 0, 0);
            acc = __builtin_amdgcn_mfma_f32_16x16x32_bf16(A1, Bl1, acc, 0, 0, 0);
        }
        const float th = fabsf(theta[0]);
        const float al = fabsf(alpha[0]);
        const float be = fabsf(beta[0]);
#pragma unroll
        for (int reg = 0; reg < 4; ++reg) {
            const int row = rowbase + b * 4 + reg;
            float pf = acc[reg];
            float ps = sigmoid5(pf);
            float pa = pf * ps;
            unsigned short h0,l0,h1,l1;
            split_bf16(th * pa - al * (1.0f - ps), h0, l0);
            split_bf16(-be * pa, h1, l1);
            Ph[row * 32 + m]      = h0;  Pl[row * 32 + m]      = l0;
            Ph[row * 32 + 16 + m] = h1;  Pl[row * 32 + 16 + m] = l1;
        }
    } else {
#pragma unroll 2
        for (int kstep = 0; kstep < 32; ++kstep) {
            const float* pk = rowp + kstep * 32 + b * 8;
            float4 v0 = *(const float4*)(pk);
            float4 v1 = *(const float4*)(pk + 4);
            unsigned short h0,l0,h1,l1,h2,l2,h3,l3,h4,l4,h5,l5,h6,l6,h7,l7;
            split_bf16(v0.x, h0, l0); split_bf16(v0.y, h1, l1);
            split_bf16(v0.z, h2, l2); split_bf16(v0.w, h3, l3);
            split_bf16(v1.x, h4, l4); split_bf16(v1.y, h5, l5);
            split_bf16(v1.z, h6, l6); split_bf16(v1.w, h7, l7);
            short8 Ah, Al;
            Ah[0]=(short)h0; Ah[1]=(short)h1; Ah[2]=(short)h2; Ah[3]=(short)h3;
            Ah[4]=(short)h4; Ah[5]=(short)h5; Ah[6]=(short)h6; Ah[7]=(short)h7;
            Al[0]=(short)l0; Al[1]=(short)l1; Al[2]=(short)l2; Al[3]=(short)l3;
            Al[4]=(short)l4; Al[5]=(short)l5; Al[6]=(short)l6; Al[7]=(short)l7;
            const short8 Bh = *(const short8*)(BFh + ((size_t)kstep * 64 + lane) * 8);
            const short8 Bl = *(const short8*)(BFl + ((size_t)kstep * 64 + lane) * 8);
            acc = __builtin_amdgcn_mfma_f32_16x16x32_bf16(Ah, Bh, acc, 0, 0, 0);
            acc = __builtin_amdgcn_mfma_f32_16x16x32_bf16(Ah, Bl, acc, 0, 0, 0);
            acc = __builtin_amdgcn_mfma_f32_16x16x32_bf16(Al, Bh, acc, 0, 0, 0);
            acc = __builtin_amdgcn_mfma_f32_16x16x32_bf16(Al, Bl, acc, 0, 0, 0);
        }
#pragma unroll
        for (int reg = 0; reg < 4; ++reg) {
            const int row = rowbase + b * 4 + reg;
            float xf = acc[reg];
            float xs = sigmoid5(xf);
            unsigned short h0,l0,h1,l1;
            split_bf16(xf * xs, h0, l0);
            split_bf16(1.0f - xs, h1, l1);
            Xh[row * 32 + m]      = h0;  Xl[row * 32 + m]      = l0;
            Xh[row * 32 + 16 + m] = h1;  Xl[row * 32 + 16 + m] = l1;
        }
    }
}

// ------- main: R14 body verbatim — 45.3 us standalone (R18 algebra) -------
__global__ __launch_bounds__(64) void main_mm_mfma(
    const unsigned short* __restrict__ Xh, const unsigned short* __restrict__ Xl,
    const unsigned short* __restrict__ Ph, const unsigned short* __restrict__ Pl,
    float* __restrict__ out)
{
    __shared__ float lds[16][128];      // 8 KiB, wave-private (1 wave/block)
    const int lane  = threadIdx.x & 63;
    const int m     = lane & 15;
    const int b     = lane >> 4;
    const int nbase = blockIdx.y * 16;
    const int ob    = blockIdx.x * 128;

    const size_t boff = (size_t)(nbase + m) * 32 + b * 8;
    const short8 Bh = *(const short8*)(Xh + boff);
    const short8 Bl = *(const short8*)(Xl + boff);

    const int wsw = 4 * (m & 7);
    float* myrow = &lds[m][0];
#pragma unroll
    for (int t = 0; t < 8; ++t) {
        const size_t aoff = (size_t)(ob + t * 16 + m) * 32 + b * 8;
        const short8 Ah = *(const short8*)(Ph + aoff);
        const short8 Al = *(const short8*)(Pl + aoff);
        f32x4 acc = {0.f, 0.f, 0.f, 0.f};
        acc = __builtin_amdgcn_mfma_f32_16x16x32_bf16(Ah, Bh, acc, 0, 0, 0);
        acc = __builtin_amdgcn_mfma_f32_16x16x32_bf16(Ah, Bl, acc, 0, 0, 0);
        acc = __builtin_amdgcn_mfma_f32_16x16x32_bf16(Al, Bh, acc, 0, 0, 0);
        acc = __builtin_amdgcn_mfma_f32_16x16x32_bf16(Al, Bl, acc, 0, 0, 0);
        *(f32x4*)(myrow + ((t * 16 + b * 4) ^ wsw)) = acc;
    }

    const float* src = &lds[0][0];
#pragma unroll
    for (int r = 0; r < 16; ++r) {
        f32x2 v = *(const f32x2*)(src + r * 128 + ((lane * 2) ^ (4 * (r & 7))));
        f32x2* dst = (f32x2*)(out + (size_t)(nbase + r) * NPROTO + ob + lane * 2);
        __builtin_nontemporal_store(v, dst);
    }
}

extern "C" void kernel_launch(void* const* d_in, const int* in_sizes, int n_in,
                              void* d_out, int out_size, void* d_ws, size_t ws_size,
                              hipStream_t stream) {
    const float* x     = (const float*)d_in[0];
    const float* feat  = (const float*)d_in[1];
    const float* proto = (const float*)d_in[2];
    const float* theta = (const float*)d_in[3];
    const float* alpha = (const float*)d_in[4];
    const float* beta  = (const float*)d_in[5];
    float* out = (float*)d_out;

    unsigned short* Ph  = (unsigned short*)d_ws;          // 256 KiB
    unsigned short* Pl  = Ph + (size_t)NPROTO * 32;       // 256 KiB
    unsigned short* Xh  = Pl + (size_t)NPROTO * 32;       // 1 MiB
    unsigned short* Xl  = Xh + (size_t)NROWS * 32;        // 1 MiB
    unsigned short* BFh = Xl + (size_t)NROWS * 32;        // 32 KiB
    unsigned short* BFl = BFh + (size_t)2048 * 8;         // 32 KiB

    bfrag_kernel<<<dim3(8), 256, 0, stream>>>(feat, BFh, BFl);
    prep<<<dim3(NPROTO / 16 + NROWS / 16), 64, 0, stream>>>(
        x, proto, theta, alpha, beta, BFh, BFl, Ph, Pl, Xh, Xl);
    main_mm_mfma<<<dim3(NPROTO / 128, NROWS / 16), 64, 0, stream>>>(Xh, Xl, Ph, Pl, out);
}

// Round 22
// 71.813 us; speedup vs baseline: 3.2458x; 1.0497x over previous
//
#include <hip/hip_runtime.h>
#include <hip/hip_bf16.h>
#include <math.h>

#define NF     16
#define INF    1024
#define NPROTO 4096
#define NROWS  16384

typedef __attribute__((ext_vector_type(8))) short short8;   // 8 bf16 (4 VGPRs)
typedef __attribute__((ext_vector_type(4))) float f32x4;
typedef __attribute__((ext_vector_type(2))) float f32x2;

__device__ __forceinline__ float bf16_rne(float x) {
    unsigned u = __float_as_uint(x);
    unsigned r = (u + 0x7FFFu + ((u >> 16) & 1u)) & 0xFFFF0000u;
    return __uint_as_float(r);
}
__device__ __forceinline__ unsigned short bf16_hi(float v) {
    unsigned u = __float_as_uint(v);
    return (unsigned short)((u + 0x7FFFu + ((u >> 16) & 1u)) >> 16);
}
// split f32 v into bf16 hi + bf16 lo (v ~= hi + lo)
__device__ __forceinline__ void split_bf16(float v, unsigned short& hi, unsigned short& lo) {
    unsigned u  = __float_as_uint(v);
    unsigned r  = u + 0x7FFFu + ((u >> 16) & 1u);
    hi = (unsigned short)(r >> 16);
    float hf = __uint_as_float(r & 0xFFFF0000u);
    lo = bf16_hi(v - hf);
}
__device__ __forceinline__ float sigmoid5(float z) {
    return 1.0f / (1.0f + __expf(-5.0f * z));
}

// ---- B-fragment precompute: feat -> bf16 hi/lo MFMA fragments ----
__global__ __launch_bounds__(256) void bfrag_kernel(
    const float* __restrict__ feat,
    unsigned short* __restrict__ BFh, unsigned short* __restrict__ BFl)
{
    const int t = blockIdx.x * 256 + threadIdx.x;    // 0..2047
    const int kstep = t >> 6, lane = t & 63;
    const int n = lane & 15, b = lane >> 4;
    const float* src = feat + (size_t)n * INF + kstep * 32 + b * 8;
    float4 v0 = *(const float4*)(src);
    float4 v1 = *(const float4*)(src + 4);
    unsigned short h[8], l[8];
    split_bf16(v0.x, h[0], l[0]); split_bf16(v0.y, h[1], l[1]);
    split_bf16(v0.z, h[2], l[2]); split_bf16(v0.w, h[3], l[3]);
    split_bf16(v1.x, h[4], l[4]); split_bf16(v1.y, h[5], l[5]);
    split_bf16(v1.z, h[6], l[6]); split_bf16(v1.w, h[7], l[7]);
#pragma unroll
    for (int e = 0; e < 8; ++e) { BFh[t * 8 + e] = h[e]; BFl[t * 8 + e] = l[e]; }
}

// ---- R22 prep: K-split MFMA projection (4 waves/block share one 16-row tile) ----
// R21 was ~1.25 waves/SIMD (1280 single-wave blocks) -> whole kernel ran at
// ONE wave's serial latency. Now: block = 4 waves, wave w does ksteps
// [8w,8w+8) (pe: groups [4w,4w+4), shfl stays in-wave), partial f32x4 accs
// summed via 4 KB LDS + one barrier -> 5120 waves (20/CU), chain/4.
__global__ __launch_bounds__(256, 4) void prep(
    const float* __restrict__ x, const float* __restrict__ proto,
    const float* __restrict__ theta, const float* __restrict__ alpha,
    const float* __restrict__ beta,
    const unsigned short* __restrict__ BFh, const unsigned short* __restrict__ BFl,
    unsigned short* __restrict__ Ph, unsigned short* __restrict__ Pl,
    unsigned short* __restrict__ Xh, unsigned short* __restrict__ Xl)
{
    __shared__ f32x4 red[4][64];        // 4 KB partial-acc reduce buffer
    const int lane = threadIdx.x & 63;
    const int w    = threadIdx.x >> 6;
    const int m = lane & 15, b = lane >> 4;
    const int blk = blockIdx.x;
    const bool is_pe = (blk < NPROTO / 16);
    const int rowbase = (is_pe ? blk : blk - NPROTO / 16) * 16;
    const float* rowp = (is_pe ? proto : x) + (size_t)(rowbase + m) * INF;

    f32x4 acc = {0.f, 0.f, 0.f, 0.f};

    if (is_pe) {
#pragma unroll
        for (int gi = 0; gi < 4; ++gi) {
            const int g = w * 4 + gi;   // 64-elem quant group; ksteps 2g, 2g+1
            const float* pg = rowp + g * 64 + b * 8;
            float4 v0 = *(const float4*)(pg);
            float4 v1 = *(const float4*)(pg + 4);
            float4 v2 = *(const float4*)(pg + 32);
            float4 v3 = *(const float4*)(pg + 36);
            float w0 = bf16_rne(v0.x), w1 = bf16_rne(v0.y), w2 = bf16_rne(v0.z), w3 = bf16_rne(v0.w);
            float w4 = bf16_rne(v1.x), w5 = bf16_rne(v1.y), w6 = bf16_rne(v1.z), w7 = bf16_rne(v1.w);
            float w8 = bf16_rne(v2.x), w9 = bf16_rne(v2.y), wa = bf16_rne(v2.z), wb = bf16_rne(v2.w);
            float wc = bf16_rne(v3.x), wd = bf16_rne(v3.y), we = bf16_rne(v3.z), wf = bf16_rne(v3.w);
            float p0 = ((fabsf(w0) + fabsf(w1)) + fabsf(w2)) + fabsf(w3);
            float p1 = ((fabsf(w4) + fabsf(w5)) + fabsf(w6)) + fabsf(w7);
            float p2 = ((fabsf(w8) + fabsf(w9)) + fabsf(wa)) + fabsf(wb);
            float p3 = ((fabsf(wc) + fabsf(wd)) + fabsf(we)) + fabsf(wf);
            float p = ((p0 + p1) + p2) + p3;
            p += __shfl_xor(p, 16, 64);
            p += __shfl_xor(p, 32, 64);
            float scale = fmaxf(bf16_rne(p * (1.0f / 64.0f)), 1e-8f);
            float inv = 1.0f / scale;
            short8 A0, A1;
            A0[0] = (short)bf16_hi(fminf(fmaxf(rintf(bf16_rne(w0 * inv)), -1.f), 1.f) * scale);
            A0[1] = (short)bf16_hi(fminf(fmaxf(rintf(bf16_rne(w1 * inv)), -1.f), 1.f) * scale);
            A0[2] = (short)bf16_hi(fminf(fmaxf(rintf(bf16_rne(w2 * inv)), -1.f), 1.f) * scale);
            A0[3] = (short)bf16_hi(fminf(fmaxf(rintf(bf16_rne(w3 * inv)), -1.f), 1.f) * scale);
            A0[4] = (short)bf16_hi(fminf(fmaxf(rintf(bf16_rne(w4 * inv)), -1.f), 1.f) * scale);
            A0[5] = (short)bf16_hi(fminf(fmaxf(rintf(bf16_rne(w5 * inv)), -1.f), 1.f) * scale);
            A0[6] = (short)bf16_hi(fminf(fmaxf(rintf(bf16_rne(w6 * inv)), -1.f), 1.f) * scale);
            A0[7] = (short)bf16_hi(fminf(fmaxf(rintf(bf16_rne(w7 * inv)), -1.f), 1.f) * scale);
            A1[0] = (short)bf16_hi(fminf(fmaxf(rintf(bf16_rne(w8 * inv)), -1.f), 1.f) * scale);
            A1[1] = (short)bf16_hi(fminf(fmaxf(rintf(bf16_rne(w9 * inv)), -1.f), 1.f) * scale);
            A1[2] = (short)bf16_hi(fminf(fmaxf(rintf(bf16_rne(wa * inv)), -1.f), 1.f) * scale);
            A1[3] = (short)bf16_hi(fminf(fmaxf(rintf(bf16_rne(wb * inv)), -1.f), 1.f) * scale);
            A1[4] = (short)bf16_hi(fminf(fmaxf(rintf(bf16_rne(wc * inv)), -1.f), 1.f) * scale);
            A1[5] = (short)bf16_hi(fminf(fmaxf(rintf(bf16_rne(wd * inv)), -1.f), 1.f) * scale);
            A1[6] = (short)bf16_hi(fminf(fmaxf(rintf(bf16_rne(we * inv)), -1.f), 1.f) * scale);
            A1[7] = (short)bf16_hi(fminf(fmaxf(rintf(bf16_rne(wf * inv)), -1.f), 1.f) * scale);
            const short8 Bh0 = *(const short8*)(BFh + ((size_t)(2 * g) * 64 + lane) * 8);
            const short8 Bl0 = *(const short8*)(BFl + ((size_t)(2 * g) * 64 + lane) * 8);
            const short8 Bh1 = *(const short8*)(BFh + ((size_t)(2 * g + 1) * 64 + lane) * 8);
            const short8 Bl1 = *(const short8*)(BFl + ((size_t)(2 * g + 1) * 64 + lane) * 8);
            acc = __builtin_amdgcn_mfma_f32_16x16x32_bf16(A0, Bh0, acc, 0, 0, 0);
            acc = __builtin_amdgcn_mfma_f32_16x16x32_bf16(A0, Bl0, acc, 0, 0, 0);
            acc = __builtin_amdgcn_mfma_f32_16x16x32_bf16(A1, Bh1, acc, 0, 0, 0);
            acc = __builtin_amdgcn_mfma_f32_16x16x32_bf16(A1, Bl1, acc, 0, 0, 0);
        }
    } else {
#pragma unroll
        for (int ki = 0; ki < 8; ++ki) {
            const int kstep = w * 8 + ki;
            const float* pk = rowp + kstep * 32 + b * 8;
            float4 v0 = *(const float4*)(pk);
            float4 v1 = *(const float4*)(pk + 4);
            unsigned short h0,l0,h1,l1,h2,l2,h3,l3,h4,l4,h5,l5,h6,l6,h7,l7;
            split_bf16(v0.x, h0, l0); split_bf16(v0.y, h1, l1);
            split_bf16(v0.z, h2, l2); split_bf16(v0.w, h3, l3);
            split_bf16(v1.x, h4, l4); split_bf16(v1.y, h5, l5);
            split_bf16(v1.z, h6, l6); split_bf16(v1.w, h7, l7);
            short8 Ah, Al;
            Ah[0]=(short)h0; Ah[1]=(short)h1; Ah[2]=(short)h2; Ah[3]=(short)h3;
            Ah[4]=(short)h4; Ah[5]=(short)h5; Ah[6]=(short)h6; Ah[7]=(short)h7;
            Al[0]=(short)l0; Al[1]=(short)l1; Al[2]=(short)l2; Al[3]=(short)l3;
            Al[4]=(short)l4; Al[5]=(short)l5; Al[6]=(short)l6; Al[7]=(short)l7;
            const short8 Bh = *(const short8*)(BFh + ((size_t)kstep * 64 + lane) * 8);
            const short8 Bl = *(const short8*)(BFl + ((size_t)kstep * 64 + lane) * 8);
            acc = __builtin_amdgcn_mfma_f32_16x16x32_bf16(Ah, Bh, acc, 0, 0, 0);
            acc = __builtin_amdgcn_mfma_f32_16x16x32_bf16(Ah, Bl, acc, 0, 0, 0);
            acc = __builtin_amdgcn_mfma_f32_16x16x32_bf16(Al, Bh, acc, 0, 0, 0);
            acc = __builtin_amdgcn_mfma_f32_16x16x32_bf16(Al, Bl, acc, 0, 0, 0);
        }
    }

    // ---- cross-wave K reduce ----
    red[w][lane] = acc;
    __syncthreads();
    if (w == 0) {
        f32x4 a0 = red[0][lane], a1 = red[1][lane], a2 = red[2][lane], a3 = red[3][lane];
        f32x4 tot = (a0 + a1) + (a2 + a3);
        if (is_pe) {
            const float th = fabsf(theta[0]);
            const float al = fabsf(alpha[0]);
            const float be = fabsf(beta[0]);
#pragma unroll
            for (int reg = 0; reg < 4; ++reg) {
                const int row = rowbase + b * 4 + reg;
                float pf = tot[reg];
                float ps = sigmoid5(pf);
                float pa = pf * ps;
                unsigned short h0,l0,h1,l1;
                split_bf16(th * pa - al * (1.0f - ps), h0, l0);
                split_bf16(-be * pa, h1, l1);
                Ph[row * 32 + m]      = h0;  Pl[row * 32 + m]      = l0;
                Ph[row * 32 + 16 + m] = h1;  Pl[row * 32 + 16 + m] = l1;
            }
        } else {
#pragma unroll
            for (int reg = 0; reg < 4; ++reg) {
                const int row = rowbase + b * 4 + reg;
                float xf = tot[reg];
                float xs = sigmoid5(xf);
                unsigned short h0,l0,h1,l1;
                split_bf16(xf * xs, h0, l0);
                split_bf16(1.0f - xs, h1, l1);
                Xh[row * 32 + m]      = h0;  Xl[row * 32 + m]      = l0;
                Xh[row * 32 + 16 + m] = h1;  Xl[row * 32 + 16 + m] = l1;
            }
        }
    }
}

// ------- main: R14 body verbatim — 45.3 us standalone (R18 algebra) -------
__global__ __launch_bounds__(64) void main_mm_mfma(
    const unsigned short* __restrict__ Xh, const unsigned short* __restrict__ Xl,
    const unsigned short* __restrict__ Ph, const unsigned short* __restrict__ Pl,
    float* __restrict__ out)
{
    __shared__ float lds[16][128];      // 8 KiB, wave-private (1 wave/block)
    const int lane  = threadIdx.x & 63;
    const int m     = lane & 15;
    const int b     = lane >> 4;
    const int nbase = blockIdx.y * 16;
    const int ob    = blockIdx.x * 128;

    const size_t boff = (size_t)(nbase + m) * 32 + b * 8;
    const short8 Bh = *(const short8*)(Xh + boff);
    const short8 Bl = *(const short8*)(Xl + boff);

    const int wsw = 4 * (m & 7);
    float* myrow = &lds[m][0];
#pragma unroll
    for (int t = 0; t < 8; ++t) {
        const size_t aoff = (size_t)(ob + t * 16 + m) * 32 + b * 8;
        const short8 Ah = *(const short8*)(Ph + aoff);
        const short8 Al = *(const short8*)(Pl + aoff);
        f32x4 acc = {0.f, 0.f, 0.f, 0.f};
        acc = __builtin_amdgcn_mfma_f32_16x16x32_bf16(Ah, Bh, acc, 0, 0, 0);
        acc = __builtin_amdgcn_mfma_f32_16x16x32_bf16(Ah, Bl, acc, 0, 0, 0);
        acc = __builtin_amdgcn_mfma_f32_16x16x32_bf16(Al, Bh, acc, 0, 0, 0);
        acc = __builtin_amdgcn_mfma_f32_16x16x32_bf16(Al, Bl, acc, 0, 0, 0);
        *(f32x4*)(myrow + ((t * 16 + b * 4) ^ wsw)) = acc;
    }

    const float* src = &lds[0][0];
#pragma unroll
    for (int r = 0; r < 16; ++r) {
        f32x2 v = *(const f32x2*)(src + r * 128 + ((lane * 2) ^ (4 * (r & 7))));
        f32x2* dst = (f32x2*)(out + (size_t)(nbase + r) * NPROTO + ob + lane * 2);
        __builtin_nontemporal_store(v, dst);
    }
}

extern "C" void kernel_launch(void* const* d_in, const int* in_sizes, int n_in,
                              void* d_out, int out_size, void* d_ws, size_t ws_size,
                              hipStream_t stream) {
    const float* x     = (const float*)d_in[0];
    const float* feat  = (const float*)d_in[1];
    const float* proto = (const float*)d_in[2];
    const float* theta = (const float*)d_in[3];
    const float* alpha = (const float*)d_in[4];
    const float* beta  = (const float*)d_in[5];
    float* out = (float*)d_out;

    unsigned short* Ph  = (unsigned short*)d_ws;          // 256 KiB
    unsigned short* Pl  = Ph + (size_t)NPROTO * 32;       // 256 KiB
    unsigned short* Xh  = Pl + (size_t)NPROTO * 32;       // 1 MiB
    unsigned short* Xl  = Xh + (size_t)NROWS * 32;        // 1 MiB
    unsigned short* BFh = Xl + (size_t)NROWS * 32;        // 32 KiB
    unsigned short* BFl = BFh + (size_t)2048 * 8;         // 32 KiB

    bfrag_kernel<<<dim3(8), 256, 0, stream>>>(feat, BFh, BFl);
    prep<<<dim3(NPROTO / 16 + NROWS / 16), 256, 0, stream>>>(
        x, proto, theta, alpha, beta, BFh, BFl, Ph, Pl, Xh, Xl);
    main_mm_mfma<<<dim3(NPROTO / 128, NROWS / 16), 64, 0, stream>>>(Xh, Xl, Ph, Pl, out);
}

// Round 23
// 69.677 us; speedup vs baseline: 3.3453x; 1.0307x over previous
//
#include <hip/hip_runtime.h>
#include <hip/hip_bf16.h>
#include <math.h>

#define NF     16
#define INF    1024
#define NPROTO 4096
#define NROWS  16384

typedef __attribute__((ext_vector_type(8))) short short8;   // 8 bf16 (4 VGPRs)
typedef __attribute__((ext_vector_type(4))) float f32x4;
typedef __attribute__((ext_vector_type(2))) float f32x2;

__device__ __forceinline__ float bf16_rne(float x) {
    unsigned u = __float_as_uint(x);
    unsigned r = (u + 0x7FFFu + ((u >> 16) & 1u)) & 0xFFFF0000u;
    return __uint_as_float(r);
}
__device__ __forceinline__ unsigned short bf16_hi(float v) {
    unsigned u = __float_as_uint(v);
    return (unsigned short)((u + 0x7FFFu + ((u >> 16) & 1u)) >> 16);
}
// split f32 v into bf16 hi + bf16 lo (v ~= hi + lo)
__device__ __forceinline__ void split_bf16(float v, unsigned short& hi, unsigned short& lo) {
    unsigned u  = __float_as_uint(v);
    unsigned r  = u + 0x7FFFu + ((u >> 16) & 1u);
    hi = (unsigned short)(r >> 16);
    float hf = __uint_as_float(r & 0xFFFF0000u);
    lo = bf16_hi(v - hf);
}
__device__ __forceinline__ float sigmoid5(float z) {
    return 1.0f / (1.0f + __expf(-5.0f * z));
}

// ---- B-fragment precompute: feat -> bf16 hi/lo MFMA fragments ----
__global__ __launch_bounds__(256) void bfrag_kernel(
    const float* __restrict__ feat,
    unsigned short* __restrict__ BFh, unsigned short* __restrict__ BFl)
{
    const int t = blockIdx.x * 256 + threadIdx.x;    // 0..2047
    const int kstep = t >> 6, lane = t & 63;
    const int n = lane & 15, b = lane >> 4;
    const float* src = feat + (size_t)n * INF + kstep * 32 + b * 8;
    float4 v0 = *(const float4*)(src);
    float4 v1 = *(const float4*)(src + 4);
    unsigned short h[8], l[8];
    split_bf16(v0.x, h[0], l[0]); split_bf16(v0.y, h[1], l[1]);
    split_bf16(v0.z, h[2], l[2]); split_bf16(v0.w, h[3], l[3]);
    split_bf16(v1.x, h[4], l[4]); split_bf16(v1.y, h[5], l[5]);
    split_bf16(v1.z, h[6], l[6]); split_bf16(v1.w, h[7], l[7]);
#pragma unroll
    for (int e = 0; e < 8; ++e) { BFh[t * 8 + e] = h[e]; BFl[t * 8 + e] = l[e]; }
}

// ---- R22 prep (unchanged, incl. Pl writes, for clean A/B attribution) ----
__global__ __launch_bounds__(256, 4) void prep(
    const float* __restrict__ x, const float* __restrict__ proto,
    const float* __restrict__ theta, const float* __restrict__ alpha,
    const float* __restrict__ beta,
    const unsigned short* __restrict__ BFh, const unsigned short* __restrict__ BFl,
    unsigned short* __restrict__ Ph, unsigned short* __restrict__ Pl,
    unsigned short* __restrict__ Xh, unsigned short* __restrict__ Xl)
{
    __shared__ f32x4 red[4][64];        // 4 KB partial-acc reduce buffer
    const int lane = threadIdx.x & 63;
    const int w    = threadIdx.x >> 6;
    const int m = lane & 15, b = lane >> 4;
    const int blk = blockIdx.x;
    const bool is_pe = (blk < NPROTO / 16);
    const int rowbase = (is_pe ? blk : blk - NPROTO / 16) * 16;
    const float* rowp = (is_pe ? proto : x) + (size_t)(rowbase + m) * INF;

    f32x4 acc = {0.f, 0.f, 0.f, 0.f};

    if (is_pe) {
#pragma unroll
        for (int gi = 0; gi < 4; ++gi) {
            const int g = w * 4 + gi;   // 64-elem quant group; ksteps 2g, 2g+1
            const float* pg = rowp + g * 64 + b * 8;
            float4 v0 = *(const float4*)(pg);
            float4 v1 = *(const float4*)(pg + 4);
            float4 v2 = *(const float4*)(pg + 32);
            float4 v3 = *(const float4*)(pg + 36);
            float w0 = bf16_rne(v0.x), w1 = bf16_rne(v0.y), w2 = bf16_rne(v0.z), w3 = bf16_rne(v0.w);
            float w4 = bf16_rne(v1.x), w5 = bf16_rne(v1.y), w6 = bf16_rne(v1.z), w7 = bf16_rne(v1.w);
            float w8 = bf16_rne(v2.x), w9 = bf16_rne(v2.y), wa = bf16_rne(v2.z), wb = bf16_rne(v2.w);
            float wc = bf16_rne(v3.x), wd = bf16_rne(v3.y), we = bf16_rne(v3.z), wf = bf16_rne(v3.w);
            float p0 = ((fabsf(w0) + fabsf(w1)) + fabsf(w2)) + fabsf(w3);
            float p1 = ((fabsf(w4) + fabsf(w5)) + fabsf(w6)) + fabsf(w7);
            float p2 = ((fabsf(w8) + fabsf(w9)) + fabsf(wa)) + fabsf(wb);
            float p3 = ((fabsf(wc) + fabsf(wd)) + fabsf(we)) + fabsf(wf);
            float p = ((p0 + p1) + p2) + p3;
            p += __shfl_xor(p, 16, 64);
            p += __shfl_xor(p, 32, 64);
            float scale = fmaxf(bf16_rne(p * (1.0f / 64.0f)), 1e-8f);
            float inv = 1.0f / scale;
            short8 A0, A1;
            A0[0] = (short)bf16_hi(fminf(fmaxf(rintf(bf16_rne(w0 * inv)), -1.f), 1.f) * scale);
            A0[1] = (short)bf16_hi(fminf(fmaxf(rintf(bf16_rne(w1 * inv)), -1.f), 1.f) * scale);
            A0[2] = (short)bf16_hi(fminf(fmaxf(rintf(bf16_rne(w2 * inv)), -1.f), 1.f) * scale);
            A0[3] = (short)bf16_hi(fminf(fmaxf(rintf(bf16_rne(w3 * inv)), -1.f), 1.f) * scale);
            A0[4] = (short)bf16_hi(fminf(fmaxf(rintf(bf16_rne(w4 * inv)), -1.f), 1.f) * scale);
            A0[5] = (short)bf16_hi(fminf(fmaxf(rintf(bf16_rne(w5 * inv)), -1.f), 1.f) * scale);
            A0[6] = (short)bf16_hi(fminf(fmaxf(rintf(bf16_rne(w6 * inv)), -1.f), 1.f) * scale);
            A0[7] = (short)bf16_hi(fminf(fmaxf(rintf(bf16_rne(w7 * inv)), -1.f), 1.f) * scale);
            A1[0] = (short)bf16_hi(fminf(fmaxf(rintf(bf16_rne(w8 * inv)), -1.f), 1.f) * scale);
            A1[1] = (short)bf16_hi(fminf(fmaxf(rintf(bf16_rne(w9 * inv)), -1.f), 1.f) * scale);
            A1[2] = (short)bf16_hi(fminf(fmaxf(rintf(bf16_rne(wa * inv)), -1.f), 1.f) * scale);
            A1[3] = (short)bf16_hi(fminf(fmaxf(rintf(bf16_rne(wb * inv)), -1.f), 1.f) * scale);
            A1[4] = (short)bf16_hi(fminf(fmaxf(rintf(bf16_rne(wc * inv)), -1.f), 1.f) * scale);
            A1[5] = (short)bf16_hi(fminf(fmaxf(rintf(bf16_rne(wd * inv)), -1.f), 1.f) * scale);
            A1[6] = (short)bf16_hi(fminf(fmaxf(rintf(bf16_rne(we * inv)), -1.f), 1.f) * scale);
            A1[7] = (short)bf16_hi(fminf(fmaxf(rintf(bf16_rne(wf * inv)), -1.f), 1.f) * scale);
            const short8 Bh0 = *(const short8*)(BFh + ((size_t)(2 * g) * 64 + lane) * 8);
            const short8 Bl0 = *(const short8*)(BFl + ((size_t)(2 * g) * 64 + lane) * 8);
            const short8 Bh1 = *(const short8*)(BFh + ((size_t)(2 * g + 1) * 64 + lane) * 8);
            const short8 Bl1 = *(const short8*)(BFl + ((size_t)(2 * g + 1) * 64 + lane) * 8);
            acc = __builtin_amdgcn_mfma_f32_16x16x32_bf16(A0, Bh0, acc, 0, 0, 0);
            acc = __builtin_amdgcn_mfma_f32_16x16x32_bf16(A0, Bl0, acc, 0, 0, 0);
            acc = __builtin_amdgcn_mfma_f32_16x16x32_bf16(A1, Bh1, acc, 0, 0, 0);
            acc = __builtin_amdgcn_mfma_f32_16x16x32_bf16(A1, Bl1, acc, 0, 0, 0);
        }
    } else {
#pragma unroll
        for (int ki = 0; ki < 8; ++ki) {
            const int kstep = w * 8 + ki;
            const float* pk = rowp + kstep * 32 + b * 8;
            float4 v0 = *(const float4*)(pk);
            float4 v1 = *(const float4*)(pk + 4);
            unsigned short h0,l0,h1,l1,h2,l2,h3,l3,h4,l4,h5,l5,h6,l6,h7,l7;
            split_bf16(v0.x, h0, l0); split_bf16(v0.y, h1, l1);
            split_bf16(v0.z, h2, l2); split_bf16(v0.w, h3, l3);
            split_bf16(v1.x, h4, l4); split_bf16(v1.y, h5, l5);
            split_bf16(v1.z, h6, l6); split_bf16(v1.w, h7, l7);
            short8 Ah, Al;
            Ah[0]=(short)h0; Ah[1]=(short)h1; Ah[2]=(short)h2; Ah[3]=(short)h3;
            Ah[4]=(short)h4; Ah[5]=(short)h5; Ah[6]=(short)h6; Ah[7]=(short)h7;
            Al[0]=(short)l0; Al[1]=(short)l1; Al[2]=(short)l2; Al[3]=(short)l3;
            Al[4]=(short)l4; Al[5]=(short)l5; Al[6]=(short)l6; Al[7]=(short)l7;
            const short8 Bh = *(const short8*)(BFh + ((size_t)kstep * 64 + lane) * 8);
            const short8 Bl = *(const short8*)(BFl + ((size_t)kstep * 64 + lane) * 8);
            acc = __builtin_amdgcn_mfma_f32_16x16x32_bf16(Ah, Bh, acc, 0, 0, 0);
            acc = __builtin_amdgcn_mfma_f32_16x16x32_bf16(Ah, Bl, acc, 0, 0, 0);
            acc = __builtin_amdgcn_mfma_f32_16x16x32_bf16(Al, Bh, acc, 0, 0, 0);
            acc = __builtin_amdgcn_mfma_f32_16x16x32_bf16(Al, Bl, acc, 0, 0, 0);
        }
    }

    // ---- cross-wave K reduce ----
    red[w][lane] = acc;
    __syncthreads();
    if (w == 0) {
        f32x4 a0 = red[0][lane], a1 = red[1][lane], a2 = red[2][lane], a3 = red[3][lane];
        f32x4 tot = (a0 + a1) + (a2 + a3);
        if (is_pe) {
            const float th = fabsf(theta[0]);
            const float al = fabsf(alpha[0]);
            const float be = fabsf(beta[0]);
#pragma unroll
            for (int reg = 0; reg < 4; ++reg) {
                const int row = rowbase + b * 4 + reg;
                float pf = tot[reg];
                float ps = sigmoid5(pf);
                float pa = pf * ps;
                unsigned short h0,l0,h1,l1;
                split_bf16(th * pa - al * (1.0f - ps), h0, l0);
                split_bf16(-be * pa, h1, l1);
                Ph[row * 32 + m]      = h0;  Pl[row * 32 + m]      = l0;
                Ph[row * 32 + 16 + m] = h1;  Pl[row * 32 + 16 + m] = l1;
            }
        } else {
#pragma unroll
            for (int reg = 0; reg < 4; ++reg) {
                const int row = rowbase + b * 4 + reg;
                float xf = tot[reg];
                float xs = sigmoid5(xf);
                unsigned short h0,l0,h1,l1;
                split_bf16(xf * xs, h0, l0);
                split_bf16(1.0f - xs, h1, l1);
                Xh[row * 32 + m]      = h0;  Xl[row * 32 + m]      = l0;
                Xh[row * 32 + 16 + m] = h1;  Xl[row * 32 + 16 + m] = l1;
            }
        }
    }
}

// ------- main R23: Pe HI-PLANE ONLY (A/B vs R22's 45.3 us) -------
// Per t-tile: 1 Pe load + 2 MFMA (was 2 + 4). Pe L2 read halves
// (512->256 MB aggregate), MFMA 32->16/block. Xe keeps hi+lo.
// If main was load/MFMA-limited -> ~40 us; if write-bound -> null.
__global__ __launch_bounds__(64) void main_mm_mfma(
    const unsigned short* __restrict__ Xh, const unsigned short* __restrict__ Xl,
    const unsigned short* __restrict__ Ph,
    float* __restrict__ out)
{
    __shared__ float lds[16][128];      // 8 KiB, wave-private (1 wave/block)
    const int lane  = threadIdx.x & 63;
    const int m     = lane & 15;
    const int b     = lane >> 4;
    const int nbase = blockIdx.y * 16;
    const int ob    = blockIdx.x * 128;

    const size_t boff = (size_t)(nbase + m) * 32 + b * 8;
    const short8 Bh = *(const short8*)(Xh + boff);
    const short8 Bl = *(const short8*)(Xl + boff);

    const int wsw = 4 * (m & 7);
    float* myrow = &lds[m][0];
#pragma unroll
    for (int t = 0; t < 8; ++t) {
        const size_t aoff = (size_t)(ob + t * 16 + m) * 32 + b * 8;
        const short8 Ah = *(const short8*)(Ph + aoff);
        f32x4 acc = {0.f, 0.f, 0.f, 0.f};
        acc = __builtin_amdgcn_mfma_f32_16x16x32_bf16(Ah, Bh, acc, 0, 0, 0);
        acc = __builtin_amdgcn_mfma_f32_16x16x32_bf16(Ah, Bl, acc, 0, 0, 0);
        *(f32x4*)(myrow + ((t * 16 + b * 4) ^ wsw)) = acc;
    }

    const float* src = &lds[0][0];
#pragma unroll
    for (int r = 0; r < 16; ++r) {
        f32x2 v = *(const f32x2*)(src + r * 128 + ((lane * 2) ^ (4 * (r & 7))));
        f32x2* dst = (f32x2*)(out + (size_t)(nbase + r) * NPROTO + ob + lane * 2);
        __builtin_nontemporal_store(v, dst);
    }
}

extern "C" void kernel_launch(void* const* d_in, const int* in_sizes, int n_in,
                              void* d_out, int out_size, void* d_ws, size_t ws_size,
                              hipStream_t stream) {
    const float* x     = (const float*)d_in[0];
    const float* feat  = (const float*)d_in[1];
    const float* proto = (const float*)d_in[2];
    const float* theta = (const float*)d_in[3];
    const float* alpha = (const float*)d_in[4];
    const float* beta  = (const float*)d_in[5];
    float* out = (float*)d_out;

    unsigned short* Ph  = (unsigned short*)d_ws;          // 256 KiB
    unsigned short* Pl  = Ph + (size_t)NPROTO * 32;       // 256 KiB (written, unused by main)
    unsigned short* Xh  = Pl + (size_t)NPROTO * 32;       // 1 MiB
    unsigned short* Xl  = Xh + (size_t)NROWS * 32;        // 1 MiB
    unsigned short* BFh = Xl + (size_t)NROWS * 32;        // 32 KiB
    unsigned short* BFl = BFh + (size_t)2048 * 8;         // 32 KiB

    bfrag_kernel<<<dim3(8), 256, 0, stream>>>(feat, BFh, BFl);
    prep<<<dim3(NPROTO / 16 + NROWS / 16), 256, 0, stream>>>(
        x, proto, theta, alpha, beta, BFh, BFl, Ph, Pl, Xh, Xl);
    main_mm_mfma<<<dim3(NPROTO / 128, NROWS / 16), 64, 0, stream>>>(Xh, Xl, Ph, out);
}